// Round 2
// baseline (507.147 us; speedup 1.0000x reference)
//
#include <hip/hip_runtime.h>
#include <stdint.h>
#include <math.h>

// W8A8 int8 GEMM, y = x @ W^T (int32) + rint(bias), out fp32.
// M=8192 (4*2048), N=4096, K=4096.
// HARNESS NOTE: integer inputs arrive as int32 (const int*), so a pack pass
// converts X/W to true int8 in d_ws first (X @ 0, W @ +32MB; needs 48MB ws).
// GEMM: m97-style 128x128 tile, BK=64 (int8 bytes), 2-phase double-buffered
// LDS with global_load_lds width=16, mfma_i32_32x32x32_i8.

typedef int i32x4 __attribute__((ext_vector_type(4)));
typedef int i32x16 __attribute__((ext_vector_type(16)));

static constexpr int Mdim = 8192;
static constexpr int Ndim = 4096;
static constexpr int Kdim = 4096;
static constexpr int BM = 128;
static constexpr int BN = 128;
static constexpr int BKb = 64;              // K bytes per tile step
static constexpr int NKT = Kdim / BKb;      // 64 iterations
// Per-buffer LDS: A 128x64 int8 = 8192 B (layout [4 kslot][128 row][16 B]),
//                 B same at +8192. Two buffers -> 32 KiB.
static constexpr int BUF_BYTES = 16384;

typedef const __attribute__((address_space(1))) unsigned int gu32;
typedef __attribute__((address_space(3))) unsigned int lu32;

__device__ __forceinline__ void gload_lds16(const int8_t* g, char* l) {
    __builtin_amdgcn_global_load_lds((gu32*)g, (lu32*)l, 16, 0, 0);
}

// ---- pack: int32 (values in [-127,127)) -> int8, 4 elems/thread/iter ----
__global__ void pack_i32_to_i8(const int* __restrict__ in,
                               unsigned int* __restrict__ out, int n4) {
    int idx = blockIdx.x * blockDim.x + threadIdx.x;
    int stride = gridDim.x * blockDim.x;
    for (int i = idx; i < n4; i += stride) {
        i32x4 v = ((const i32x4*)in)[i];
        unsigned int o = ((unsigned)v[0] & 0xffu)
                       | (((unsigned)v[1] & 0xffu) << 8)
                       | (((unsigned)v[2] & 0xffu) << 16)
                       | (((unsigned)v[3]) << 24);
        out[i] = o;
    }
}

__global__ __launch_bounds__(256, 2) void w8a8_gemm_kernel(
    const int8_t* __restrict__ X, const int8_t* __restrict__ Wt,
    const float* __restrict__ bias, float* __restrict__ out)
{
    __shared__ char smem[2 * BUF_BYTES];

    const int tid   = threadIdx.x;
    const int w     = tid >> 6;   // wave 0..3
    const int l     = tid & 63;   // lane
    const int lrow  = l & 31;
    const int khalf = l >> 5;     // 0/1 -> which 16-byte K half of the 32-K MFMA
    const int wr    = w >> 1;     // wave row 0..1  (64-row sub-tile)
    const int wc    = w & 1;      // wave col 0..1  (64-col sub-tile)

    const int bm = blockIdx.x * BM;
    const int bn = blockIdx.y * BN;

    // ---- staging addresses (wave w owns k-slot w; 2 statements cover 128 rows) ----
    const int8_t* gA0 = X  + (long)(bm +      l) * Kdim + w * 16;
    const int8_t* gA1 = X  + (long)(bm + 64 + l) * Kdim + w * 16;
    const int8_t* gB0 = Wt + (long)(bn +      l) * Kdim + w * 16;
    const int8_t* gB1 = Wt + (long)(bn + 64 + l) * Kdim + w * 16;
    // LDS dest: linear = wave-uniform base + lane*16 (required by global_load_lds)
    const int lA0 = (w * 128 +      l) * 16;          // slot w, rows 0..63
    const int lA1 = (w * 128 + 64 + l) * 16;          // slot w, rows 64..127
    const int lB0 = 8192 + (w * 128 +      l) * 16;
    const int lB1 = 8192 + (w * 128 + 64 + l) * 16;

    // ---- fragment read offsets ----
    // A frag (mi, ks): buf*16384 + (ks*2+khalf)*2048 + (wr*64 + mi*32 + lrow)*16
    const int aRowOff = (wr * 64 + lrow) * 16;
    const int bRowOff = (wc * 64 + lrow) * 16;

    i32x16 acc[2][2] = {};

    // ---- prologue: stage buffer 0, k=0 ----
    gload_lds16(gA0, &smem[lA0]);
    gload_lds16(gA1, &smem[lA1]);
    gload_lds16(gB0, &smem[lB0]);
    gload_lds16(gB1, &smem[lB1]);
    asm volatile("s_waitcnt vmcnt(0)" ::: "memory");
    __syncthreads();

    int buf = 0;
    for (int kt = 0; kt < NKT; ++kt) {
        // stage next K-tile into the other buffer (overlaps with compute below)
        if (kt + 1 < NKT) {
            const int kb = (kt + 1) * BKb;
            const int nb = (buf ^ 1) * BUF_BYTES;
            gload_lds16(gA0 + kb, &smem[nb + lA0]);
            gload_lds16(gA1 + kb, &smem[nb + lA1]);
            gload_lds16(gB0 + kb, &smem[nb + lB0]);
            gload_lds16(gB1 + kb, &smem[nb + lB1]);
        }

        // fragments from current buffer (lane-contiguous ds_read_b128, conflict-free)
        const char* sb = &smem[buf * BUF_BYTES];
        i32x4 af[2][2], bf[2][2];
#pragma unroll
        for (int ks = 0; ks < 2; ++ks) {
            const int slot = (ks * 2 + khalf) * 2048;
            af[0][ks] = *(const i32x4*)(sb + slot + aRowOff);
            af[1][ks] = *(const i32x4*)(sb + slot + aRowOff + 32 * 16);
            bf[0][ks] = *(const i32x4*)(sb + 8192 + slot + bRowOff);
            bf[1][ks] = *(const i32x4*)(sb + 8192 + slot + bRowOff + 32 * 16);
        }

#pragma unroll
        for (int ks = 0; ks < 2; ++ks)
#pragma unroll
            for (int mi = 0; mi < 2; ++mi)
#pragma unroll
                for (int ni = 0; ni < 2; ++ni)
                    acc[mi][ni] = __builtin_amdgcn_mfma_i32_32x32x32_i8(
                        af[mi][ks], bf[ni][ks], acc[mi][ni], 0, 0, 0);

        asm volatile("s_waitcnt vmcnt(0)" ::: "memory");
        __syncthreads();
        buf ^= 1;
    }

    // ---- epilogue: C/D layout col=lane&31, row=(reg&3)+8*(reg>>2)+4*khalf ----
#pragma unroll
    for (int ni = 0; ni < 2; ++ni) {
        const int col = bn + wc * 64 + ni * 32 + lrow;
        const float badd = rintf(bias[col]);   // round-half-even == jnp.round
#pragma unroll
        for (int mi = 0; mi < 2; ++mi) {
            const int rbase = bm + wr * 64 + mi * 32 + 4 * khalf;
#pragma unroll
            for (int r = 0; r < 16; ++r) {
                const int row = rbase + (r & 3) + 8 * (r >> 2);
                out[(long)row * Ndim + col] = (float)acc[mi][ni][r] + badd;
            }
        }
    }
}

extern "C" void kernel_launch(void* const* d_in, const int* in_sizes, int n_in,
                              void* d_out, int out_size, void* d_ws, size_t ws_size,
                              hipStream_t stream) {
    const int*   X32  = (const int*)d_in[0];   // [8192,4096] int8 values stored as int32
    const int*   W32  = (const int*)d_in[1];   // [4096,4096] int8 values stored as int32
    const float* bias = (const float*)d_in[2]; // [4096] fp32
    float* out = (float*)d_out;                // [8192,4096] fp32

    int8_t* Xp = (int8_t*)d_ws;                          // 32 MB
    int8_t* Wp = (int8_t*)d_ws + (size_t)Mdim * Kdim;    // 16 MB

    const int nX4 = Mdim * Kdim / 4;   // 8M
    const int nW4 = Ndim * Kdim / 4;   // 4M
    pack_i32_to_i8<<<2048, 256, 0, stream>>>(X32, (unsigned int*)Xp, nX4);
    pack_i32_to_i8<<<2048, 256, 0, stream>>>(W32, (unsigned int*)Wp, nW4);

    dim3 grid(Mdim / BM, Ndim / BN);  // 64 x 32
    w8a8_gemm_kernel<<<grid, dim3(256), 0, stream>>>(Xp, Wp, bias, out);
}

// Round 5
// 411.637 us; speedup vs baseline: 1.2320x; 1.2320x over previous
//
#include <hip/hip_runtime.h>
#include <stdint.h>
#include <math.h>

// W8A8 int8 GEMM, y = x @ W^T (int32) + rint(bias), out fp32.
// M=8192, N=4096, K=4096. Inputs arrive int32-encoded; pack pass -> int8 in d_ws.
// GEMM: 256x256 tile, 8-phase schedule (T3+T4 counted vmcnt, T5 setprio),
// mfma_i32_16x16x64_i8, k-slot-major LDS (conflict-free, no swizzle needed).
// 8 waves = 2M x 4N, per-wave output 128x64, BK=128 bytes, LDS 128 KiB 2-dbuf.

typedef int i32x4 __attribute__((ext_vector_type(4)));

static constexpr int Mdim = 8192;
static constexpr int Ndim = 4096;
static constexpr int Kdim = 4096;
static constexpr int BM = 256;
static constexpr int BN = 256;
static constexpr int BKb = 128;             // K bytes per tile step
static constexpr int NKT = Kdim / BKb;      // 32 K-tiles
// Per-buffer LDS: A [2 half][8 kslot][128 row][16B] = 32KB, B same at +32768.
static constexpr int BUF_BYTES = 65536;

typedef const __attribute__((address_space(1))) unsigned int gu32;
typedef __attribute__((address_space(3))) unsigned int lu32;

__device__ __forceinline__ void gload_lds16(const int8_t* g, char* l) {
    __builtin_amdgcn_global_load_lds((gu32*)g, (lu32*)l, 16, 0, 0);
}

// ---- pack: int32 (values in [-127,127)) -> int8, 4 elems/thread/iter ----
__global__ void pack_i32_to_i8(const int* __restrict__ in,
                               unsigned int* __restrict__ out, int n4) {
    int idx = blockIdx.x * blockDim.x + threadIdx.x;
    int stride = gridDim.x * blockDim.x;
    for (int i = idx; i < n4; i += stride) {
        i32x4 v = ((const i32x4*)in)[i];
        unsigned int o = ((unsigned)v[0] & 0xffu)
                       | (((unsigned)v[1] & 0xffu) << 8)
                       | (((unsigned)v[2] & 0xffu) << 16)
                       | (((unsigned)v[3]) << 24);
        out[i] = o;
    }
}

__global__ __launch_bounds__(512, 2) void w8a8_gemm_256(
    const int8_t* __restrict__ X, const int8_t* __restrict__ Wt,
    const float* __restrict__ bias, float* __restrict__ out)
{
    __shared__ char smem[2 * BUF_BYTES];   // 128 KiB

    const int tid = threadIdx.x;
    const int w   = tid >> 6;     // wave 0..7
    const int l   = tid & 63;
    const int fr  = l & 15;       // frag row/col
    const int fk  = l >> 4;       // k-group 0..3 (16B each)
    const int wm  = w >> 2;       // wave M 0..1 -> rows wm*128..+127
    const int wn  = w & 3;        // wave N 0..3 -> cols wn*64..+63

    const int bm = blockIdx.x * BM;
    const int bn = blockIdx.y * BN;

    // staging bases: wave w stages kslot w; lane l walks rows
    const int8_t* gA = X  + (size_t)(bm + l) * Kdim + w * 16;
    const int8_t* gB = Wt + (size_t)(bn + l) * Kdim + w * 16;
    const int ldsAw = w * 2048 + l * 16;           // + hm*16384 + s*1024 + buf
    const int ldsBw = 32768 + w * 2048 + l * 16;

    auto stageA = [&](int t, int hm) {
        const int bufo = (t & 1) * BUF_BYTES;
        const size_t ko = (size_t)t * BKb;
#pragma unroll
        for (int s = 0; s < 2; ++s)
            gload_lds16(gA + (size_t)(hm * 128 + s * 64) * Kdim + ko,
                        &smem[bufo + hm * 16384 + s * 1024 + ldsAw]);
    };
    auto stageB = [&](int t, int hn) {
        const int bufo = (t & 1) * BUF_BYTES;
        const size_t ko = (size_t)t * BKb;
#pragma unroll
        for (int s = 0; s < 2; ++s)
            gload_lds16(gB + (size_t)(hn * 128 + s * 64) * Kdim + ko,
                        &smem[bufo + hn * 16384 + s * 1024 + ldsBw]);
    };

    // fragment read bases (k-slot-major: [half][kslot][row][16B])
    const int aBase = wm * 16384 + fk * 2048 + fr * 16;
    const int bBase = 32768 + (wn >> 1) * 16384 + fk * 2048
                    + ((wn & 1) * 64 + fr) * 16;

    i32x4 acc[8][4] = {};
    i32x4 a[4][2], b[4][2];

    // ---- prologue: queue = [B0(0),B1(0),A0(0),A1(0),B0(1),B1(1)] ----
    stageB(0, 0); stageB(0, 1); stageA(0, 0); stageA(0, 1);
    stageB(1, 0); stageB(1, 1);
    asm volatile("s_waitcnt vmcnt(4)" ::: "memory");   // tile 0 fully landed
    __syncthreads();

    for (int t = 0; t < NKT; ++t) {
        const int p = (t & 1) * BUF_BYTES;

        // ---- P1: quadrant mi 0-3 x ni 0-1 ----
#pragma unroll
        for (int ks = 0; ks < 2; ++ks) {
#pragma unroll
            for (int j = 0; j < 4; ++j)
                a[j][ks] = *(const i32x4*)&smem[p + aBase + ks * 8192 + j * 256];
#pragma unroll
            for (int ni = 0; ni < 2; ++ni)
                b[ni][ks] = *(const i32x4*)&smem[p + bBase + ks * 8192 + ni * 256];
        }
        if (t + 1 < NKT) stageA(t + 1, 0);
        __builtin_amdgcn_s_barrier();
        asm volatile("s_waitcnt lgkmcnt(0)" ::: "memory");
        __builtin_amdgcn_sched_barrier(0);
        __builtin_amdgcn_s_setprio(1);
#pragma unroll
        for (int ks = 0; ks < 2; ++ks)
#pragma unroll
            for (int j = 0; j < 4; ++j)
#pragma unroll
                for (int ni = 0; ni < 2; ++ni)
                    acc[j][ni] = __builtin_amdgcn_mfma_i32_16x16x64_i8(
                        a[j][ks], b[ni][ks], acc[j][ni], 0, 0, 0);
        __builtin_amdgcn_s_setprio(0);
        __builtin_amdgcn_s_barrier();

        // ---- P2: quadrant mi 0-3 x ni 2-3 ----
#pragma unroll
        for (int ks = 0; ks < 2; ++ks)
#pragma unroll
            for (int ni = 2; ni < 4; ++ni)
                b[ni][ks] = *(const i32x4*)&smem[p + bBase + ks * 8192 + ni * 256];
        if (t + 1 < NKT) stageA(t + 1, 1);
        __builtin_amdgcn_s_barrier();
        asm volatile("s_waitcnt lgkmcnt(0)" ::: "memory");
        __builtin_amdgcn_sched_barrier(0);
        __builtin_amdgcn_s_setprio(1);
#pragma unroll
        for (int ks = 0; ks < 2; ++ks)
#pragma unroll
            for (int j = 0; j < 4; ++j)
#pragma unroll
                for (int ni = 2; ni < 4; ++ni)
                    acc[j][ni] = __builtin_amdgcn_mfma_i32_16x16x64_i8(
                        a[j][ks], b[ni][ks], acc[j][ni], 0, 0, 0);
        __builtin_amdgcn_s_setprio(0);
        __builtin_amdgcn_s_barrier();

        // ---- P3: quadrant mi 4-7 x ni 0-1 (reload a, reuse b[0..1]) ----
#pragma unroll
        for (int ks = 0; ks < 2; ++ks)
#pragma unroll
            for (int j = 0; j < 4; ++j)
                a[j][ks] = *(const i32x4*)&smem[p + aBase + ks * 8192 + 1024 + j * 256];
        if (t + 2 < NKT) stageB(t + 2, 0);
        __builtin_amdgcn_s_barrier();
        asm volatile("s_waitcnt lgkmcnt(0)" ::: "memory");
        __builtin_amdgcn_sched_barrier(0);
        __builtin_amdgcn_s_setprio(1);
#pragma unroll
        for (int ks = 0; ks < 2; ++ks)
#pragma unroll
            for (int j = 0; j < 4; ++j)
#pragma unroll
                for (int ni = 0; ni < 2; ++ni)
                    acc[4 + j][ni] = __builtin_amdgcn_mfma_i32_16x16x64_i8(
                        a[j][ks], b[ni][ks], acc[4 + j][ni], 0, 0, 0);
        __builtin_amdgcn_s_setprio(0);
        __builtin_amdgcn_s_barrier();

        // ---- P4: quadrant mi 4-7 x ni 2-3 (all regs live) ----
        if (t + 2 < NKT) stageB(t + 2, 1);
        __builtin_amdgcn_s_barrier();
        __builtin_amdgcn_s_setprio(1);
#pragma unroll
        for (int ks = 0; ks < 2; ++ks)
#pragma unroll
            for (int j = 0; j < 4; ++j)
#pragma unroll
                for (int ni = 2; ni < 4; ++ni)
                    acc[4 + j][ni] = __builtin_amdgcn_mfma_i32_16x16x64_i8(
                        a[j][ks], b[ni][ks], acc[4 + j][ni], 0, 0, 0);
        __builtin_amdgcn_s_setprio(0);
        // counted wait for next tile's 4 half-tiles (never 0 mid-loop)
        if (t + 1 < NKT) {
            if (t + 1 == NKT - 1) asm volatile("s_waitcnt vmcnt(0)" ::: "memory");
            else                  asm volatile("s_waitcnt vmcnt(4)" ::: "memory");
        }
        __builtin_amdgcn_s_barrier();
    }

    // ---- epilogue: C/D col=lane&15, row=(lane>>4)*4+reg ----
    float bv[4];
#pragma unroll
    for (int ni = 0; ni < 4; ++ni)
        bv[ni] = rintf(bias[bn + wn * 64 + ni * 16 + fr]);
#pragma unroll
    for (int mi = 0; mi < 8; ++mi) {
        const int rbase = bm + wm * 128 + mi * 16 + fk * 4;
#pragma unroll
        for (int ni = 0; ni < 4; ++ni) {
            const int col = bn + wn * 64 + ni * 16 + fr;
#pragma unroll
            for (int r = 0; r < 4; ++r)
                out[(size_t)(rbase + r) * Ndim + col] = (float)acc[mi][ni][r] + bv[ni];
        }
    }
}

extern "C" void kernel_launch(void* const* d_in, const int* in_sizes, int n_in,
                              void* d_out, int out_size, void* d_ws, size_t ws_size,
                              hipStream_t stream) {
    const int*   X32  = (const int*)d_in[0];   // [8192,4096] int8 values as int32
    const int*   W32  = (const int*)d_in[1];   // [4096,4096] int8 values as int32
    const float* bias = (const float*)d_in[2]; // [4096] fp32
    float* out = (float*)d_out;                // [8192,4096] fp32

    int8_t* Xp = (int8_t*)d_ws;                          // 32 MB
    int8_t* Wp = (int8_t*)d_ws + (size_t)Mdim * Kdim;    // 16 MB

    const int nX4 = Mdim * Kdim / 4;
    const int nW4 = Ndim * Kdim / 4;
    pack_i32_to_i8<<<2048, 256, 0, stream>>>(X32, (unsigned int*)Xp, nX4);
    pack_i32_to_i8<<<2048, 256, 0, stream>>>(W32, (unsigned int*)Wp, nW4);

    dim3 grid(Mdim / BM, Ndim / BN);  // 32 x 16
    w8a8_gemm_256<<<grid, dim3(512), 0, stream>>>(Xp, Wp, bias, out);
}